// Round 11
// baseline (136.216 us; speedup 1.0000x reference)
//
#include <hip/hip_runtime.h>
#include <math.h>

// Problem shape (fixed by setup_inputs): B=4, N=M=4096, D=3, fp32.
#define BATCH 4
#define NPTS  4096
#define RPB   256                 // threads per block
#define ROWS  4                   // rows (X points) per thread
#define ROWS_PER_BLOCK (RPB * ROWS)          // 1024
#define CHUNKS (NPTS / ROWS_PER_BLOCK)       // 4 row-chunks
#define SEGS  32                  // m-split -> 4*32*4*2 = 1024 blocks (4/CU)
#define SEG_LEN (NPTS / SEGS)     // 128 Y points staged per block
#define NGROUPS (2 * BATCH * CHUNKS)         // 32 groups of SEGS blocks

#define FP_SCALE 268435456.0      // 2^28 fixed-point scale for deterministic sum

// ws layout: [0..8) u64 total | [8..12) u32 global counter |
//            [64..192) u32 gcount[NGROUPS] |
//            [256 ..) float part[NGROUPS][SEGS][ROWS_PER_BLOCK]  (4 MB)

__global__ void ahd_init(unsigned long long* __restrict__ total,
                         unsigned int* __restrict__ counter,
                         unsigned int* __restrict__ gcount) {
    if (threadIdx.x == 0) { *total = 0ULL; *counter = 0u; }
    if (threadIdx.x < NGROUPS) gcount[threadIdx.x] = 0u;
}

// Fused: R3/R9's proven min loop (1024 blocks = 4/CU, simple 4-op/pair,
// broadcast float4 LDS) + in-kernel two-level last-arriver reduction.
__global__ __launch_bounds__(RPB) void ahd_fused(
    const float* __restrict__ set1, const float* __restrict__ set2,
    float* __restrict__ part, unsigned int* __restrict__ gcount,
    unsigned long long* __restrict__ total, unsigned int* __restrict__ counter,
    float* __restrict__ out)
{
    const int dir      = blockIdx.z;
    const int b        = blockIdx.y;
    const int rowChunk = blockIdx.x / SEGS;
    const int seg      = blockIdx.x % SEGS;
    const int g        = (dir * BATCH + b) * CHUNKS + rowChunk;

    const float* __restrict__ X = dir ? set2 : set1;
    const float* __restrict__ Y = dir ? set1 : set2;

    __shared__ float4 ys[SEG_LEN];   // {y0, y1, y2, |y|^2}

    const float* ybase = Y + ((size_t)b * NPTS + (size_t)seg * SEG_LEN) * 3;
    for (int i = threadIdx.x; i < SEG_LEN; i += RPB) {
        const float y0 = ybase[i * 3 + 0];
        const float y1 = ybase[i * 3 + 1];
        const float y2 = ybase[i * 3 + 2];
        ys[i] = make_float4(y0, y1, y2, fmaf(y0, y0, fmaf(y1, y1, y2 * y2)));
    }
    __syncthreads();

    float nx0[ROWS], nx1[ROWS], nx2[ROWS], hx[ROWS], acc[ROWS];
    #pragma unroll
    for (int r = 0; r < ROWS; ++r) {
        const float* xp = X + ((size_t)b * NPTS + rowChunk * ROWS_PER_BLOCK
                               + threadIdx.x + r * RPB) * 3;
        const float x0 = xp[0], x1 = xp[1], x2 = xp[2];
        nx0[r] = -2.0f * x0;
        nx1[r] = -2.0f * x1;
        nx2[r] = -2.0f * x2;
        hx[r]  = fmaf(x0, x0, fmaf(x1, x1, x2 * x2));
        acc[r] = 3.4e38f;
    }

    // Simple j-loop (R3-proven optimum): 3 FMA + 1 fmin per pair,
    // 4 independent min chains, broadcast ds_read_b128 conflict-free.
    #pragma unroll 8
    for (int j = 0; j < SEG_LEN; ++j) {
        const float4 y = ys[j];
        #pragma unroll
        for (int r = 0; r < ROWS; ++r) {
            const float q = fmaf(nx0[r], y.x,
                            fmaf(nx1[r], y.y,
                            fmaf(nx2[r], y.z, y.w)));
            acc[r] = fminf(acc[r], q);
        }
    }

    // Per-segment partial d^2 (clamped >= 0), plain coalesced stores.
    float* dst = part + ((size_t)g * SEGS + seg) * ROWS_PER_BLOCK;
    #pragma unroll
    for (int r = 0; r < ROWS; ++r)
        dst[threadIdx.x + r * RPB] = fmaxf(acc[r] + hx[r], 0.0f);

    // Release our writes, then bump the group counter.
    __threadfence();
    __shared__ unsigned int isLast;
    if (threadIdx.x == 0)
        isLast = (atomicAdd(&gcount[g], 1u) == SEGS - 1) ? 1u : 0u;
    __syncthreads();
    if (!isLast) return;

    // Last block of the group: acquire, then reduce 32 segs x 1024 rows.
    __threadfence();
    const float* pg = part + (size_t)g * SEGS * ROWS_PER_BLOCK;
    // Thread t owns rows 4t..4t+3: float4 min across segs (coalesced 16B/lane).
    float4 m = *(const float4*)&pg[4 * threadIdx.x];
    #pragma unroll 8
    for (int s = 1; s < SEGS; ++s) {
        const float4 v = *(const float4*)&pg[s * ROWS_PER_BLOCK + 4 * threadIdx.x];
        m.x = fminf(m.x, v.x); m.y = fminf(m.y, v.y);
        m.z = fminf(m.z, v.z); m.w = fminf(m.w, v.w);
    }
    float s4 = sqrtf(m.x) + sqrtf(m.y) + sqrtf(m.z) + sqrtf(m.w);

    // wave tree-sum (deterministic order)
    #pragma unroll
    for (int off = 32; off > 0; off >>= 1)
        s4 += __shfl_down(s4, off, 64);

    __shared__ unsigned long long wsum[4];
    const int lane = threadIdx.x & 63;
    const int w    = threadIdx.x >> 6;
    if (lane == 0)
        wsum[w] = (unsigned long long)((double)s4 * FP_SCALE);
    __syncthreads();

    if (threadIdx.x == 0) {
        const unsigned long long bs = wsum[0] + wsum[1] + wsum[2] + wsum[3];
        atomicAdd(total, bs);
        __threadfence();
        const unsigned int cnt = atomicAdd(counter, 1u);
        if (cnt == (unsigned int)(NGROUPS - 1)) {
            // last group: all total-adds visible (fence + counter order)
            const unsigned long long fin = atomicAdd(total, 0ULL);
            out[0] = (float)((double)fin * (1.0 / FP_SCALE)
                             * (1.0 / (double)(BATCH * NPTS)));
        }
    }
}

extern "C" void kernel_launch(void* const* d_in, const int* in_sizes, int n_in,
                              void* d_out, int out_size, void* d_ws, size_t ws_size,
                              hipStream_t stream) {
    const float* set1 = (const float*)d_in[0];
    const float* set2 = (const float*)d_in[1];
    float* out = (float*)d_out;

    unsigned long long* total = (unsigned long long*)d_ws;
    unsigned int* counter = (unsigned int*)((char*)d_ws + 8);
    unsigned int* gcount  = (unsigned int*)((char*)d_ws + 64);
    float* part = (float*)((char*)d_ws + 256);   // 4 MB

    ahd_init<<<1, dim3(64), 0, stream>>>(total, counter, gcount);
    dim3 grid(CHUNKS * SEGS, BATCH, 2);
    ahd_fused<<<grid, dim3(RPB), 0, stream>>>(set1, set2, part, gcount,
                                              total, counter, out);
}